// Round 9
// baseline (638.478 us; speedup 1.0000x reference)
//
#include <hip/hip_runtime.h>

typedef __bf16 bf16x8 __attribute__((ext_vector_type(8)));
typedef __bf16 bf16x4 __attribute__((ext_vector_type(4)));
typedef float  f32x4  __attribute__((ext_vector_type(4)));

#define NH    16
#define SEQ   8192
#define EDIM  64
#define CHK   512
#define WCOLS 15872      // 512 + 15*1024
#define OUT0  8388608    // NH*SEQ*EDIM

#define MFMA(a, b, c) __builtin_amdgcn_mfma_f32_16x16x32_bf16((a), (b), (c), 0, 0, 0)

// ---------------------------------------------------------------------------
// Chunked attention, one block per (h, chunk, 64-row group). 2048 blocks of
// 256 threads (4 waves x 16 rows). K/V in 128-key tiles double-buffered
// through a 2x16KB LDS pool. S fully in registers. W stores via per-wave
// LDS relay, emitted as row-linear 512B bursts.
//
// THIS ROUND'S CHANGES (nt-cap theory + zero-merge):
//  1. W and O stores are PLAIN stores (L2 write-back), not nontemporal.
//     The rocclr fill reaches 6.3 TB/s through L2 at 10% occupancy; our
//     nt path appeared capped near ~2.5 TB/s regardless of segment size
//     (R7 64B -> R8 512B only gained 48us).
//  2. Zero half-window (cols colbase+512..1023, n>=1) folded back into
//     this kernel as ROW-LINEAR zero bursts issued before staging, so the
//     252MB of zeros drains under the QK/softmax/PV work instead of
//     occupying a separate 42us serial launch. Each row's full window
//     write is 4KB contiguous (relay chunks 0-3 = P, chunks 4-7 = 0).
// ---------------------------------------------------------------------------
__global__ __launch_bounds__(256, 2) void chunked_attn_kernel(
    const float* __restrict__ Qg, const float* __restrict__ Kg,
    const float* __restrict__ Vg, float* __restrict__ out)
{
    // 2 slots x 128 keys: frag layout idx=((s>>4)*8+sub)*16+(s&15), 16KB/slot
    __shared__ __align__(16) __bf16 lds_kv[2][8192];
    // per-wave P transpose buffer, double-buffered by pr parity
    __shared__ __align__(16) __bf16 lds_p[4][2][640];
    // per-wave W relay: 16 rows x (128+1) f32 (pad breaks bank conflicts)
    __shared__ __align__(16) float  lds_w[4][16 * 129];

    const int tid  = threadIdx.x;
    const int lane = tid & 63;
    const int wv   = __builtin_amdgcn_readfirstlane(tid >> 6);  // 0..3
    const int l16  = lane & 15;
    const int quad = lane >> 4;     // 0..3

    const int bid = blockIdx.x;
    const int g   = bid >> 8;       // 0..7 row group (slow dim -> XCD locality)
    const int hn  = bid & 255;
    const int h   = hn >> 4;
    const int n   = hn & 15;
    const int ns  = (n == 0) ? 0 : n - 1;   // source chunk for K/V

    const size_t qbase = ((size_t)h * SEQ + (size_t)n  * CHK) * EDIM;
    const size_t kbase = ((size_t)h * SEQ + (size_t)ns * CHK) * EDIM;
    float* __restrict__ W = out + OUT0;
    const size_t wrow0   = (size_t)h * CHK;
    const int    colbase = (n == 0) ? 0 : (CHK + (n - 1) * 2 * CHK);

    const int m0    = g * 64 + wv * 16;   // this wave's 16 q-rows (in-chunk)
    const int tmax  = g * 4 + wv;         // last 16-key s-tile with unmasked cols
    const int qrow  = m0 + l16;           // this lane's q-row
    const int ntile = (g + 2) >> 1;       // # of 128-key tiles needed (1..4)

    const float SC = 0.125f * 1.44269504088896340736f;  // scale * log2(e)

    // burst mapping shared by zero stores and W stores:
    // per instr: lanes 0-31 cover row rp*2+0, lanes 32-63 row rp*2+1,
    // each row segment 128 f32 = 512B contiguous.
    const int rr = lane >> 5;               // 0..1   burst row within pair
    const int cc = (lane & 31) * 4;         // 0..124 burst col (f32)

    // ---- zero half-window: row-linear, fire-and-forget, BEFORE staging so
    // the drain overlaps the whole block's compute. ----
    if (n > 0) {
        #pragma unroll
        for (int rp = 0; rp < 8; ++rp) {
            const int row = rp * 2 + rr;
            float* const zp = W + (wrow0 + (size_t)(m0 + row)) * WCOLS
                                + colbase + 512 + cc;
            const f32x4 z = {0.f, 0.f, 0.f, 0.f};
            #pragma unroll
            for (int ch = 0; ch < 4; ++ch)
                *(f32x4*)(zp + ch * 128) = z;
        }
    }

    // ---- Q fragments (B-layout: col q=l16, k=e=quad*8+j), scale folded ----
    bf16x8 aq0, aq1;
    {
        const float* qp = Qg + qbase + (size_t)(m0 + l16) * EDIM + quad * 8;
        float4 a = *(const float4*)(qp);
        float4 b = *(const float4*)(qp + 4);
        aq0[0]=(__bf16)(a.x*SC); aq0[1]=(__bf16)(a.y*SC); aq0[2]=(__bf16)(a.z*SC); aq0[3]=(__bf16)(a.w*SC);
        aq0[4]=(__bf16)(b.x*SC); aq0[5]=(__bf16)(b.y*SC); aq0[6]=(__bf16)(b.z*SC); aq0[7]=(__bf16)(b.w*SC);
        a = *(const float4*)(qp + 32);
        b = *(const float4*)(qp + 36);
        aq1[0]=(__bf16)(a.x*SC); aq1[1]=(__bf16)(a.y*SC); aq1[2]=(__bf16)(a.z*SC); aq1[3]=(__bf16)(a.w*SC);
        aq1[4]=(__bf16)(b.x*SC); aq1[5]=(__bf16)(b.y*SC); aq1[6]=(__bf16)(b.z*SC); aq1[7]=(__bf16)(b.w*SC);
    }

    // ---- staging helpers (256 threads, 1024 16B-slots per 128-key tile) ----
    auto stageK = [&](int kt, int slot) {
        #pragma unroll
        for (int it = 0; it < 4; ++it) {
            const int c = tid + it * 256;
            const int s = c >> 3, sub = c & 7;     // s in 0..127, e0 = sub*8
            const float* src = Kg + kbase + (size_t)(kt * 128 + s) * EDIM + sub * 8;
            const float4 a = *(const float4*)src;
            const float4 b = *(const float4*)(src + 4);
            bf16x8 t;
            t[0] = (__bf16)a.x; t[1] = (__bf16)a.y; t[2] = (__bf16)a.z; t[3] = (__bf16)a.w;
            t[4] = (__bf16)b.x; t[5] = (__bf16)b.y; t[6] = (__bf16)b.z; t[7] = (__bf16)b.w;
            const int idx = ((s >> 4) * 8 + sub) * 16 + (s & 15);
            ((bf16x8*)lds_kv[slot])[idx] = t;
        }
    };
    auto stageV = [&](int kt, int slot) {
        #pragma unroll
        for (int it = 0; it < 4; ++it) {
            const int c = tid + it * 256;
            const int e = c & 63, sb = c >> 6;     // sb in 0..15, s0 = sb*8
            bf16x8 t;
            #pragma unroll
            for (int j = 0; j < 8; ++j)
                t[j] = (__bf16)Vg[kbase + (size_t)(kt * 128 + sb * 8 + j) * EDIM + e];
            const int idx = (((sb >> 2) * 4 + (e >> 4)) * 4 + (sb & 3)) * 16 + (e & 15);
            ((bf16x8*)lds_kv[slot])[idx] = t;
        }
    };

    // ---- S stripe registers: full 512-key window per lane, init 0 so
    // skipped tiles store exact zeros to W. ----
    f32x4 st[32];
    #pragma unroll
    for (int t = 0; t < 32; ++t) st[t] = (f32x4){0.f, 0.f, 0.f, 0.f};

    // ================= QK pass: 128-key tiles, double-buffered =============
    stageK(0, 0);
    #pragma unroll
    for (int kt = 0; kt < 4; ++kt) {
        if (kt < ntile) {                       // block-uniform guard
            __syncthreads();                    // tile kt visible; slot (kt+1)&1 free
            if (kt + 1 < ntile) stageK(kt + 1, (kt + 1) & 1);
            const bf16x8* const kf = (const bf16x8*)lds_kv[kt & 1];
            #pragma unroll
            for (int tt = 0; tt < 8; ++tt) {
                const int t = kt * 8 + tt;      // global 16-key s-tile
                if (t <= tmax) {                // wave-uniform triangular skip
                    const int kb = tt * 128 + quad * 16 + l16;
                    f32x4 acc = {0.f, 0.f, 0.f, 0.f};
                    acc = MFMA(kf[kb],      aq0, acc);
                    acc = MFMA(kf[kb + 64], aq1, acc);
                    if (t == tmax) {            // only the diagonal tile needs masking
                        const int sb = t * 16 + quad * 4;
                        #pragma unroll
                        for (int r = 0; r < 4; ++r)
                            acc[r] = (sb + r <= qrow) ? acc[r] : -3.0e38f;
                    }
                    st[t] = acc;
                }
            }
        }
    }

    // ================= softmax (S fully in registers) ======================
    float mr = -3.0e38f;
    #pragma unroll
    for (int t = 0; t < 32; ++t) {
        if (t <= tmax) {
            #pragma unroll
            for (int r = 0; r < 4; ++r) mr = fmaxf(mr, st[t][r]);
        }
    }
    mr = fmaxf(mr, __shfl_xor(mr, 16));
    mr = fmaxf(mr, __shfl_xor(mr, 32));

    float lr = 0.f;
    #pragma unroll
    for (int t = 0; t < 32; ++t) {
        if (t <= tmax) {
            #pragma unroll
            for (int r = 0; r < 4; ++r) {
                const float e = __builtin_amdgcn_exp2f(st[t][r] - mr);
                st[t][r] = e;                   // masked entries -> exact 0
                lr += e;
            }
        }
    }
    lr += __shfl_xor(lr, 16);
    lr += __shfl_xor(lr, 32);
    const float ri = __builtin_amdgcn_rcpf(lr);

    #pragma unroll
    for (int t = 0; t < 32; ++t) st[t] = st[t] * ri;   // zeros stay zero

    // ---- all QK reads of lds_kv done; kick off V tile 0 so its HBM latency
    // hides under the W-store burst below ----
    __syncthreads();
    stageV(0, 0);

    // ================= W store: LDS relay -> row-linear bursts =============
    // Per 128-col chunk: stage [16][129] f32 per wave, then store 2 rows
    // (512B contiguous each) per instruction. In-wave DS ordering -- no
    // barrier needed, lds_w is wave-private. PLAIN stores: drain via L2.
    {
        float* const lw = lds_w[wv];
        #pragma unroll
        for (int ch = 0; ch < 4; ++ch) {
            #pragma unroll
            for (int tt = 0; tt < 8; ++tt)       // scatter regs into relay
                *(f32x4*)(lw + l16 * 129 + tt * 16 + quad * 4) = st[ch * 8 + tt];
            #pragma unroll
            for (int rp = 0; rp < 8; ++rp) {     // 8 instrs: 2 x 512B linear each
                const int row = rp * 2 + rr;
                const f32x4 v = *(const f32x4*)(lw + row * 129 + cc);
                *(f32x4*)(W + (wrow0 + (size_t)(m0 + row)) * WCOLS
                            + colbase + ch * 128 + cc) = v;
            }
        }
    }

    // ================= PV pass: V tiles through the same LDS pool ==========
    f32x4 o0 = {0,0,0,0}, o1 = {0,0,0,0}, o2 = {0,0,0,0}, o3 = {0,0,0,0};
    #pragma unroll
    for (int kt = 0; kt < 4; ++kt) {
        if (kt < ntile) {
            __syncthreads();
            if (kt + 1 < ntile) stageV(kt + 1, (kt + 1) & 1);
            const bf16x8* const vf = (const bf16x8*)lds_kv[kt & 1];
            #pragma unroll
            for (int pq = 0; pq < 4; ++pq) {    // 32-key sub-blocks of this tile
                const int pr = kt * 4 + pq;     // global 32-key block
                if (2 * pr <= tmax) {           // wave-uniform: P==0 beyond tmax
                    __bf16* const pbuf = lds_p[wv][pq & 1];
                    #pragma unroll
                    for (int tt = 0; tt < 2; ++tt) {
                        const int t = pr * 2 + tt;
                        bf16x4 w;
                        #pragma unroll
                        for (int r = 0; r < 4; ++r) w[r] = (__bf16)st[t][r];
                        // row q=l16, cols tt*16+quad*4..+3 (one ds_write_b64)
                        *(bf16x4*)(pbuf + l16 * 40 + tt * 16 + quad * 4) = w;
                    }
                    // A-frag read: row l16, k = quad*8..+7 (in-wave DS ordering)
                    const bf16x8 pa = *(const bf16x8*)(pbuf + l16 * 40 + quad * 8);
                    const int vb = pq * 256 + quad * 16 + l16;
                    o0 = MFMA(pa, vf[vb      ], o0);
                    o1 = MFMA(pa, vf[vb +  64], o1);
                    o2 = MFMA(pa, vf[vb + 128], o2);
                    o3 = MFMA(pa, vf[vb + 192], o3);
                }
            }
        }
    }

    // ---- write O tile (rows m0 + quad*4 + r, col l16), plain stores ----
    const int rq = m0 + quad * 4;
    const size_t ob = qbase + (size_t)rq * EDIM + l16;
    #pragma unroll
    for (int r = 0; r < 4; ++r) {
        out[ob + (size_t)r * EDIM     ] = o0[r];
        out[ob + (size_t)r * EDIM + 16] = o1[r];
        out[ob + (size_t)r * EDIM + 32] = o2[r];
        out[ob + (size_t)r * EDIM + 48] = o3[r];
    }
}

extern "C" void kernel_launch(void* const* d_in, const int* in_sizes, int n_in,
                              void* d_out, int out_size, void* d_ws, size_t ws_size,
                              hipStream_t stream) {
    const float* Q = (const float*)d_in[0];
    const float* K = (const float*)d_in[1];
    const float* V = (const float*)d_in[2];
    float* out = (float*)d_out;
    chunked_attn_kernel<<<dim3(2048), dim3(256), 0, stream>>>(Q, K, V, out);
}

// Round 11
// 633.368 us; speedup vs baseline: 1.0081x; 1.0081x over previous
//
#include <hip/hip_runtime.h>

typedef __bf16 bf16x8 __attribute__((ext_vector_type(8)));
typedef __bf16 bf16x4 __attribute__((ext_vector_type(4)));
typedef float  f32x4  __attribute__((ext_vector_type(4)));

#define NH    16
#define SEQ   8192
#define EDIM  64
#define CHK   512
#define WCOLS 15872      // 512 + 15*1024
#define OUT0  8388608    // NH*SEQ*EDIM

#define MFMA(a, b, c) __builtin_amdgcn_mfma_f32_16x16x32_bf16((a), (b), (c), 0, 0, 0)

// Raw barrier WITHOUT the vmcnt(0) drain that __syncthreads() emits.
// All inter-wave dependencies in this kernel are LDS-carried (reg-staged
// ds_write -> ds_read), so lgkmcnt(0) + s_barrier is sufficient; outstanding
// GLOBAL STORES keep draining in the background instead of stalling all
// waves at every tile boundary (the serializer per R0-R9 invariance).
// sched_barrier(0) fences guard against hipcc hoisting past the inline asm
// (guide rule #18).
__device__ __forceinline__ void lbar() {
    __builtin_amdgcn_sched_barrier(0);
    asm volatile("s_waitcnt lgkmcnt(0)" ::: "memory");
    __builtin_amdgcn_s_barrier();
    __builtin_amdgcn_sched_barrier(0);
}

// ---------------------------------------------------------------------------
// Chunked attention, one block per (h, chunk, 64-row group). 2048 blocks of
// 256 threads (4 waves x 16 rows). K/V in 128-key tiles double-buffered
// through a 2x16KB LDS pool. S fully in registers. W stores via per-wave
// LDS relay, emitted as row-linear 512B bursts, plain (L2 write-back).
//
// THIS ROUND: lgkmcnt-only barriers (see lbar) + issue-order discipline --
// zeros issued AFTER stageK0's loads, stageV0 issued BEFORE the W-store
// burst -- so no staged load's completion queues behind a store burst in
// vmcnt's in-order retirement, and no barrier forces a store drain.
// ---------------------------------------------------------------------------
__global__ __launch_bounds__(256, 2) void chunked_attn_kernel(
    const float* __restrict__ Qg, const float* __restrict__ Kg,
    const float* __restrict__ Vg, float* __restrict__ out)
{
    // 2 slots x 128 keys: frag layout idx=((s>>4)*8+sub)*16+(s&15), 16KB/slot
    __shared__ __align__(16) __bf16 lds_kv[2][8192];
    // per-wave P transpose buffer, double-buffered by pr parity
    __shared__ __align__(16) __bf16 lds_p[4][2][640];
    // per-wave W relay: 16 rows x (128+1) f32 (pad breaks bank conflicts)
    __shared__ __align__(16) float  lds_w[4][16 * 129];

    const int tid  = threadIdx.x;
    const int lane = tid & 63;
    const int wv   = __builtin_amdgcn_readfirstlane(tid >> 6);  // 0..3
    const int l16  = lane & 15;
    const int quad = lane >> 4;     // 0..3

    const int bid = blockIdx.x;
    const int g   = bid >> 8;       // 0..7 row group (slow dim -> XCD locality)
    const int hn  = bid & 255;
    const int h   = hn >> 4;
    const int n   = hn & 15;
    const int ns  = (n == 0) ? 0 : n - 1;   // source chunk for K/V

    const size_t qbase = ((size_t)h * SEQ + (size_t)n  * CHK) * EDIM;
    const size_t kbase = ((size_t)h * SEQ + (size_t)ns * CHK) * EDIM;
    float* __restrict__ W = out + OUT0;
    const size_t wrow0   = (size_t)h * CHK;
    const int    colbase = (n == 0) ? 0 : (CHK + (n - 1) * 2 * CHK);

    const int m0    = g * 64 + wv * 16;   // this wave's 16 q-rows (in-chunk)
    const int tmax  = g * 4 + wv;         // last 16-key s-tile with unmasked cols
    const int qrow  = m0 + l16;           // this lane's q-row
    const int ntile = (g + 2) >> 1;       // # of 128-key tiles needed (1..4)

    const float SC = 0.125f * 1.44269504088896340736f;  // scale * log2(e)

    // burst mapping shared by zero stores and W stores:
    // per instr: lanes 0-31 cover row rp*2+0, lanes 32-63 row rp*2+1,
    // each row segment 128 f32 = 512B contiguous.
    const int rr = lane >> 5;               // 0..1   burst row within pair
    const int cc = (lane & 31) * 4;         // 0..124 burst col (f32)

    // ---- staging helpers (256 threads, 1024 16B-slots per 128-key tile) ----
    auto stageK = [&](int kt, int slot) {
        #pragma unroll
        for (int it = 0; it < 4; ++it) {
            const int c = tid + it * 256;
            const int s = c >> 3, sub = c & 7;     // s in 0..127, e0 = sub*8
            const float* src = Kg + kbase + (size_t)(kt * 128 + s) * EDIM + sub * 8;
            const float4 a = *(const float4*)src;
            const float4 b = *(const float4*)(src + 4);
            bf16x8 t;
            t[0] = (__bf16)a.x; t[1] = (__bf16)a.y; t[2] = (__bf16)a.z; t[3] = (__bf16)a.w;
            t[4] = (__bf16)b.x; t[5] = (__bf16)b.y; t[6] = (__bf16)b.z; t[7] = (__bf16)b.w;
            const int idx = ((s >> 4) * 8 + sub) * 16 + (s & 15);
            ((bf16x8*)lds_kv[slot])[idx] = t;
        }
    };
    auto stageV = [&](int kt, int slot) {
        #pragma unroll
        for (int it = 0; it < 4; ++it) {
            const int c = tid + it * 256;
            const int e = c & 63, sb = c >> 6;     // sb in 0..15, s0 = sb*8
            bf16x8 t;
            #pragma unroll
            for (int j = 0; j < 8; ++j)
                t[j] = (__bf16)Vg[kbase + (size_t)(kt * 128 + sb * 8 + j) * EDIM + e];
            const int idx = (((sb >> 2) * 4 + (e >> 4)) * 4 + (sb & 3)) * 16 + (e & 15);
            ((bf16x8*)lds_kv[slot])[idx] = t;
        }
    };

    // ---- stage K tile 0 FIRST (loads issued before any store burst) ----
    stageK(0, 0);

    // ---- Q fragments (B-layout: col q=l16, k=e=quad*8+j), scale folded ----
    bf16x8 aq0, aq1;
    {
        const float* qp = Qg + qbase + (size_t)(m0 + l16) * EDIM + quad * 8;
        float4 a = *(const float4*)(qp);
        float4 b = *(const float4*)(qp + 4);
        aq0[0]=(__bf16)(a.x*SC); aq0[1]=(__bf16)(a.y*SC); aq0[2]=(__bf16)(a.z*SC); aq0[3]=(__bf16)(a.w*SC);
        aq0[4]=(__bf16)(b.x*SC); aq0[5]=(__bf16)(b.y*SC); aq0[6]=(__bf16)(b.z*SC); aq0[7]=(__bf16)(b.w*SC);
        a = *(const float4*)(qp + 32);
        b = *(const float4*)(qp + 36);
        aq1[0]=(__bf16)(a.x*SC); aq1[1]=(__bf16)(a.y*SC); aq1[2]=(__bf16)(a.z*SC); aq1[3]=(__bf16)(a.w*SC);
        aq1[4]=(__bf16)(b.x*SC); aq1[5]=(__bf16)(b.y*SC); aq1[6]=(__bf16)(b.z*SC); aq1[7]=(__bf16)(b.w*SC);
    }

    // ---- zero half-window (cols colbase+512..1023, n>=1): row-linear plain
    // stores issued AFTER the K0/Q loads; they drain in the background across
    // the whole kernel (no barrier waits vmcnt anymore). ----
    if (n > 0) {
        #pragma unroll
        for (int rp = 0; rp < 8; ++rp) {
            const int row = rp * 2 + rr;
            float* const zp = W + (wrow0 + (size_t)(m0 + row)) * WCOLS
                                + colbase + 512 + cc;
            const f32x4 z = {0.f, 0.f, 0.f, 0.f};
            #pragma unroll
            for (int ch = 0; ch < 4; ++ch)
                *(f32x4*)(zp + ch * 128) = z;
        }
    }

    // ---- S stripe registers: full 512-key window per lane, init 0 so
    // skipped tiles store exact zeros to W. ----
    f32x4 st[32];
    #pragma unroll
    for (int t = 0; t < 32; ++t) st[t] = (f32x4){0.f, 0.f, 0.f, 0.f};

    // ================= QK pass: 128-key tiles, double-buffered =============
    #pragma unroll
    for (int kt = 0; kt < 4; ++kt) {
        if (kt < ntile) {                       // block-uniform guard
            lbar();                             // tile kt visible; slot (kt+1)&1 free
            if (kt + 1 < ntile) stageK(kt + 1, (kt + 1) & 1);
            const bf16x8* const kf = (const bf16x8*)lds_kv[kt & 1];
            #pragma unroll
            for (int tt = 0; tt < 8; ++tt) {
                const int t = kt * 8 + tt;      // global 16-key s-tile
                if (t <= tmax) {                // wave-uniform triangular skip
                    const int kb = tt * 128 + quad * 16 + l16;
                    f32x4 acc = {0.f, 0.f, 0.f, 0.f};
                    acc = MFMA(kf[kb],      aq0, acc);
                    acc = MFMA(kf[kb + 64], aq1, acc);
                    if (t == tmax) {            // only the diagonal tile needs masking
                        const int sb = t * 16 + quad * 4;
                        #pragma unroll
                        for (int r = 0; r < 4; ++r)
                            acc[r] = (sb + r <= qrow) ? acc[r] : -3.0e38f;
                    }
                    st[t] = acc;
                }
            }
        }
    }

    // ================= softmax (S fully in registers) ======================
    float mr = -3.0e38f;
    #pragma unroll
    for (int t = 0; t < 32; ++t) {
        if (t <= tmax) {
            #pragma unroll
            for (int r = 0; r < 4; ++r) mr = fmaxf(mr, st[t][r]);
        }
    }
    mr = fmaxf(mr, __shfl_xor(mr, 16));
    mr = fmaxf(mr, __shfl_xor(mr, 32));

    float lr = 0.f;
    #pragma unroll
    for (int t = 0; t < 32; ++t) {
        if (t <= tmax) {
            #pragma unroll
            for (int r = 0; r < 4; ++r) {
                const float e = __builtin_amdgcn_exp2f(st[t][r] - mr);
                st[t][r] = e;                   // masked entries -> exact 0
                lr += e;
            }
        }
    }
    lr += __shfl_xor(lr, 16);
    lr += __shfl_xor(lr, 32);
    const float ri = __builtin_amdgcn_rcpf(lr);

    #pragma unroll
    for (int t = 0; t < 32; ++t) st[t] = st[t] * ri;   // zeros stay zero

    // ---- all QK ds_reads of lds_kv done (lgkmcnt barrier), then stage V
    // tile 0 BEFORE the W-store burst: its loads complete without queueing
    // behind the stores in vmcnt's in-order retirement. ----
    lbar();
    stageV(0, 0);

    // ================= W store: LDS relay -> row-linear bursts =============
    // Per 128-col chunk: stage [16][129] f32 per wave, then store 2 rows
    // (512B contiguous each) per instruction. In-wave DS ordering -- no
    // barrier needed, lds_w is wave-private. Plain stores: drain via L2
    // in the background (no barrier ever waits on them).
    {
        float* const lw = lds_w[wv];
        #pragma unroll
        for (int ch = 0; ch < 4; ++ch) {
            #pragma unroll
            for (int tt = 0; tt < 8; ++tt)       // scatter regs into relay
                *(f32x4*)(lw + l16 * 129 + tt * 16 + quad * 4) = st[ch * 8 + tt];
            #pragma unroll
            for (int rp = 0; rp < 8; ++rp) {     // 8 instrs: 2 x 512B linear each
                const int row = rp * 2 + rr;
                const f32x4 v = *(const f32x4*)(lw + row * 129 + cc);
                *(f32x4*)(W + (wrow0 + (size_t)(m0 + row)) * WCOLS
                            + colbase + ch * 128 + cc) = v;
            }
        }
    }

    // ================= PV pass: V tiles through the same LDS pool ==========
    f32x4 o0 = {0,0,0,0}, o1 = {0,0,0,0}, o2 = {0,0,0,0}, o3 = {0,0,0,0};
    #pragma unroll
    for (int kt = 0; kt < 4; ++kt) {
        if (kt < ntile) {
            lbar();
            if (kt + 1 < ntile) stageV(kt + 1, (kt + 1) & 1);
            const bf16x8* const vf = (const bf16x8*)lds_kv[kt & 1];
            #pragma unroll
            for (int pq = 0; pq < 4; ++pq) {    // 32-key sub-blocks of this tile
                const int pr = kt * 4 + pq;     // global 32-key block
                if (2 * pr <= tmax) {           // wave-uniform: P==0 beyond tmax
                    __bf16* const pbuf = lds_p[wv][pq & 1];
                    #pragma unroll
                    for (int tt = 0; tt < 2; ++tt) {
                        const int t = pr * 2 + tt;
                        bf16x4 w;
                        #pragma unroll
                        for (int r = 0; r < 4; ++r) w[r] = (__bf16)st[t][r];
                        // row q=l16, cols tt*16+quad*4..+3 (one ds_write_b64)
                        *(bf16x4*)(pbuf + l16 * 40 + tt * 16 + quad * 4) = w;
                    }
                    // A-frag read: row l16, k = quad*8..+7 (in-wave DS ordering)
                    const bf16x8 pa = *(const bf16x8*)(pbuf + l16 * 40 + quad * 8);
                    const int vb = pq * 256 + quad * 16 + l16;
                    o0 = MFMA(pa, vf[vb      ], o0);
                    o1 = MFMA(pa, vf[vb +  64], o1);
                    o2 = MFMA(pa, vf[vb + 128], o2);
                    o3 = MFMA(pa, vf[vb + 192], o3);
                }
            }
        }
    }

    // ---- write O tile (rows m0 + quad*4 + r, col l16), plain stores ----
    const int rq = m0 + quad * 4;
    const size_t ob = qbase + (size_t)rq * EDIM + l16;
    #pragma unroll
    for (int r = 0; r < 4; ++r) {
        out[ob + (size_t)r * EDIM     ] = o0[r];
        out[ob + (size_t)r * EDIM + 16] = o1[r];
        out[ob + (size_t)r * EDIM + 32] = o2[r];
        out[ob + (size_t)r * EDIM + 48] = o3[r];
    }
}

extern "C" void kernel_launch(void* const* d_in, const int* in_sizes, int n_in,
                              void* d_out, int out_size, void* d_ws, size_t ws_size,
                              hipStream_t stream) {
    const float* Q = (const float*)d_in[0];
    const float* K = (const float*)d_in[1];
    const float* V = (const float*)d_in[2];
    float* out = (float*)d_out;
    chunked_attn_kernel<<<dim3(2048), dim3(256), 0, stream>>>(Q, K, V, out);
}